// Round 11
// baseline (50629.034 us; speedup 1.0000x reference)
//
#include <hip/hip_runtime.h>

#define NB 64
#define NNODE 1085
#define HIST 24
#define PRED 24
#define HDIM 64
#define FMD 11
#define FD 12
#define NE 17360
#define NROWS (NB*NNODE)     // 69440
#define WPAR 8192            // waves in gather partition (2048 blocks)
#define SZT ((long)NROWS*FD) // f32 per t-slice, (n,f,b) layout

// Layouts:
//  f32 node tensors (t,n,f,b): addr = ((t*NNODE+n)*FD + f)*64 + b
//  bf16 hi/lo h:  hbf[hop][row][128]  (hi 0..63, lo 64..127), row = n*64+b
//  bf16 hi/lo Wt: [hop][ncol=192][k=192] k:0..23 Wx^T hi, 24..31 0, 32..95 Wh^T hi; 96..191 lo

typedef float v4 __attribute__((ext_vector_type(4)));
typedef float f32x4 __attribute__((ext_vector_type(4)));
typedef short short8 __attribute__((ext_vector_type(8)));

__device__ __forceinline__ float sigm(float x){ return 1.0f/(1.0f + __expf(-x)); }
__device__ __forceinline__ float tanh_f(float x){ return 1.0f - 2.0f/(__expf(2.0f*x)+1.0f); }
__device__ __forceinline__ unsigned short f2bf(float f){
    union { float f; unsigned u; } v; v.f = f;
    unsigned r = v.u + 0x7FFF + ((v.u >> 16) & 1);
    return (unsigned short)(r >> 16);
}
__device__ __forceinline__ float bf2f(unsigned short u){
    union { unsigned u; float f; } v; v.u = ((unsigned)u)<<16; return v.f;
}

// ---------------- CSR build ----------------
__global__ void csr_count_k(const int* __restrict__ dst, int* __restrict__ deg)
{
    int e = blockIdx.x*256 + threadIdx.x;
    if (e < NE) atomicAdd(&deg[dst[e]], 1);
}

__global__ __launch_bounds__(1024) void csr_scan_k(const int* __restrict__ deg,
                                                   int* __restrict__ offs, int* __restrict__ curs)
{
    __shared__ int s[2][2048];
    int t = threadIdx.x;
    for (int i=t;i<2048;i+=1024) s[0][i] = (i<NNODE) ? deg[i] : 0;
    __syncthreads();
    int cur = 0;
    for (int d=1; d<2048; d<<=1){
        for (int i=t;i<2048;i+=1024){
            int v = s[cur][i];
            if (i>=d) v += s[cur][i-d];
            s[cur^1][i] = v;
        }
        __syncthreads();
        cur ^= 1;
    }
    for (int i=t;i<=NNODE;i+=1024){
        int v = (i==0) ? 0 : s[cur][i-1];
        offs[i] = v;
        if (i<NNODE) curs[i] = v;
    }
}

__global__ void csr_fill_k(const int* __restrict__ dst, const int* __restrict__ src,
                           int* __restrict__ curs, int* __restrict__ esrc)
{
    int e = blockIdx.x*256 + threadIdx.x;
    if (e < NE){
        int d = dst[e];
        int p = atomicAdd(&curs[d], 1);
        esrc[p] = src[e];
    }
}

__global__ void csr_part_k(const int* __restrict__ offs, int* __restrict__ wpart, int npart)
{
    int w = blockIdx.x*256 + threadIdx.x;
    if (w > npart) return;
    if (w == 0)     { wpart[0] = 0;         return; }
    if (w == npart) { wpart[npart] = NNODE; return; }
    int target = (int)(((long)w * NE) / npart);
    int lo = 0, hi = NNODE;
    while (lo < hi){ int mid = (lo+hi)>>1; if (offs[mid] >= target) hi = mid; else lo = mid+1; }
    wpart[w] = lo;
}

// ---------------- one-time prep: W -> transposed hi/lo bf16, bias pack ----------------
__global__ void prep_k(const float* __restrict__ Wx, const float* __restrict__ Wh,
                       const float* __restrict__ bx, const float* __restrict__ bh,
                       unsigned short* __restrict__ Wt, float* __restrict__ bpack)
{
    int id = blockIdx.x*256 + threadIdx.x;
    if (id < 3*192*192){
        int hop = id/(192*192); int rem = id - hop*192*192;
        int n = rem/192, kk = rem - n*192;
        int k2 = (kk < 96) ? kk : kk - 96;
        float v = 0.f;
        if (k2 < 24)       v = Wx[hop*24*192 + k2*192 + n];
        else if (k2 >= 32) v = Wh[hop*64*192 + (k2-32)*192 + n];
        unsigned short hi = f2bf(v);
        Wt[id] = (kk < 96) ? hi : f2bf(v - bf2f(hi));
    }
    if (id < 3*4*64){
        int hop = id/256; int rem = id - hop*256;
        int g = rem>>6, c = rem&63;
        const float* bxk = bx + hop*192; const float* bhk = bh + hop*192;
        float v;
        if (g==0)      v = bxk[c]     + bhk[c];
        else if (g==1) v = bxk[64+c]  + bhk[64+c];
        else if (g==2) v = bxk[128+c];
        else           v = bhk[128+c];
        bpack[id] = v;
    }
}

// ---------------- hist feature build ----------------
__global__ void build_hist_k(const float* __restrict__ x_hist, const float* __restrict__ enc_misc,
                             int t0, int T, float* __restrict__ xn_all)
{
    long idx = (long)blockIdx.x*256 + threadIdx.x;
    if (idx >= (long)T*NROWS) return;
    int b = (int)(idx & 63);
    long nn = idx >> 6;
    int ti = (int)(nn / NNODE);
    int n  = (int)(nn - (long)ti*NNODE);
    int t  = t0 + ti;
    float* xp = xn_all + (long)ti*SZT + (long)n*FD*64 + b;
    xp[0] = x_hist[((long)b*HIST + t)*NNODE + n];
    const float* fp = enc_misc + (((long)b*HIST + (t+1))*NNODE + n)*FMD;
    #pragma unroll
    for (int i=0;i<FMD;i++) xp[(1+i)*64] = fp[i];
}

// ---------------- pred-0 feature build ----------------
__global__ void build_xn_k(const float* __restrict__ x_hist,
                           const float* __restrict__ dec,
                           float* __restrict__ xn)
{
    int idx = blockIdx.x*256 + threadIdx.x;
    if (idx >= NROWS) return;
    int b = idx & 63, n = idx >> 6;
    float* xp = xn + (long)n*FD*64 + b;
    xp[0] = x_hist[((long)b*HIST + (HIST-1))*NNODE + n];
    const float* fp = dec + ((long)b*PRED*NNODE + n)*FMD;
    #pragma unroll
    for (int i=0;i<FMD;i++) xp[(1+i)*64] = fp[i];
}

// ---------------- GNN hop: lane=batch, wave=node-range, in-kernel slice loop ----------------
__global__ __launch_bounds__(256,4) void gnn_gather_k(const float* __restrict__ xin,
    const float* __restrict__ We, const float* __restrict__ be,
    const int* __restrict__ esrc, const int* __restrict__ offs,
    const int* __restrict__ wpart, int T, float* __restrict__ xout)
{
    __shared__ float w_s[288];
    __shared__ float be_s[12];
    const int tid = threadIdx.x;
    for (int i=tid;i<288;i+=256) w_s[i]=We[i];
    if (tid<12) be_s[tid]=be[tid];
    __syncthreads();

    const int lane = tid & 63;
    const int wave = (blockIdx.x*256 + tid) >> 6;   // 0..WPAR-1
    const int n0 = wpart[wave], n1 = wpart[wave+1];

    for (int ti=0; ti<T; ++ti){                     // slices serialize -> L2 stays hot
        const float* x = xin + (long)ti*SZT;
        float* xo = xout + (long)ti*SZT;
        for (int n=n0; n<n1; ++n){
            float xd[12], part[12], acc[12];
            const float* xb = x + (long)n*768 + lane;
            #pragma unroll
            for (int f=0;f<12;f++) xd[f] = xb[f*64];
            #pragma unroll
            for (int f=0;f<12;f++){ part[f]=be_s[f]; acc[f]=0.f; }
            #pragma unroll
            for (int f=0;f<12;f++){
                float xv = xd[f];
                const float* wrow = &w_s[(12+f)*12];
                #pragma unroll
                for (int j=0;j<12;j++) part[j] += xv*wrow[j];
            }
            const int e0 = offs[n], e1 = offs[n+1];
            for (int idx=e0; idx<e1; ++idx){
                int s2 = esrc[idx];
                const float* xsb = x + (long)s2*768 + lane;
                float m[12];
                #pragma unroll
                for (int f=0;f<12;f++) m[f]=part[f];
                #pragma unroll
                for (int f=0;f<12;f++){
                    float xv = xsb[f*64];
                    const float* wrow = &w_s[f*12];
                    #pragma unroll
                    for (int j=0;j<12;j++) m[j] += xv*wrow[j];
                }
                #pragma unroll
                for (int f=0;f<12;f++) acc[f] += fmaxf(m[f],0.f);
            }
            float* xob = xo + (long)n*768 + lane;
            #pragma unroll
            for (int f=0;f<12;f++) xob[f*64] = xd[f] + acc[f];
        }
    }
}

// ---------------- split-precision MFMA GRU: 4 nodes/block, grid (272, 3) ----------------
__global__ __launch_bounds__(256,2) void gru_mfma_k(
    const float* __restrict__ xg_base, long k_stride,
    const float* __restrict__ xn,
    const unsigned short* __restrict__ Wt,              // [hop][192][192]
    const float* __restrict__ bpack,                    // [hop][4][64]
    unsigned short* __restrict__ hbf)                   // [hop][NROWS][128] hi/lo
{
    __shared__ __align__(16) unsigned short Wt_s[192][200];
    const int tid = threadIdx.x;
    const int hop = blockIdx.y;

    const unsigned short* wtg = Wt + (size_t)hop*192*192;
    #pragma unroll
    for (int it=0; it<18; ++it){
        int i = tid + it*256;
        int r = i/24, o = i - r*24;
        *(short8*)&Wt_s[r][o*8] = *(const short8*)&wtg[r*192 + o*8];
    }
    __syncthreads();

    const int w = tid>>6, l = tid&63, lr = l&15, lk = l>>4;
    const int b = w*16 + lr;
    const float* bp = bpack + hop*256;

    const int nend = min(blockIdx.x*4 + 4, NNODE);
    for (int n = blockIdx.x*4; n < nend; ++n){
        const long rowA = (long)n*64 + b;

        short8 a0hi = short8(0), a0lo = short8(0);
        if (lk < 3){
            const float* xgn = xg_base + (long)hop*k_stride + (long)n*768 + b;
            const float* xnn = xn + (long)n*768 + b;
            #pragma unroll
            for (int i=0;i<8;i++){
                int k = lk*8 + i;
                float v = (k<12) ? xgn[k*64] : xnn[(k-12)*64];
                unsigned short hi = f2bf(v);
                a0hi[i] = (short)hi;
                a0lo[i] = (short)f2bf(v - bf2f(hi));
            }
        }
        const unsigned short* hb = hbf + ((long)hop*NROWS + rowA)*128;
        short8 a1hi = *(const short8*)&hb[lk*8];
        short8 a2hi = *(const short8*)&hb[32 + lk*8];
        short8 a1lo = *(const short8*)&hb[64 + lk*8];
        short8 a2lo = *(const short8*)&hb[96 + lk*8];

        f32x4 accRZ[8], accNX[4], accNH[4];
        #pragma unroll
        for (int i=0;i<8;i++) accRZ[i] = f32x4(0.f);
        #pragma unroll
        for (int i=0;i<4;i++){ accNX[i] = f32x4(0.f); accNH[i] = f32x4(0.f); }

        #pragma unroll
        for (int nt=0; nt<12; ++nt){
            const unsigned short* wc = &Wt_s[nt*16 + lr][0];
            short8 b0h = *(const short8*)&wc[lk*8];
            short8 b1h = *(const short8*)&wc[32 + lk*8];
            short8 b2h = *(const short8*)&wc[64 + lk*8];
            short8 b0l = *(const short8*)&wc[96 + lk*8];
            short8 b1l = *(const short8*)&wc[128 + lk*8];
            short8 b2l = *(const short8*)&wc[160 + lk*8];
            if (nt < 8){
                f32x4 acc = accRZ[nt];
                acc = __builtin_amdgcn_mfma_f32_16x16x32_bf16(a0hi, b0h, acc, 0,0,0);
                acc = __builtin_amdgcn_mfma_f32_16x16x32_bf16(a0lo, b0h, acc, 0,0,0);
                acc = __builtin_amdgcn_mfma_f32_16x16x32_bf16(a0hi, b0l, acc, 0,0,0);
                acc = __builtin_amdgcn_mfma_f32_16x16x32_bf16(a1hi, b1h, acc, 0,0,0);
                acc = __builtin_amdgcn_mfma_f32_16x16x32_bf16(a1lo, b1h, acc, 0,0,0);
                acc = __builtin_amdgcn_mfma_f32_16x16x32_bf16(a1hi, b1l, acc, 0,0,0);
                acc = __builtin_amdgcn_mfma_f32_16x16x32_bf16(a2hi, b2h, acc, 0,0,0);
                acc = __builtin_amdgcn_mfma_f32_16x16x32_bf16(a2lo, b2h, acc, 0,0,0);
                acc = __builtin_amdgcn_mfma_f32_16x16x32_bf16(a2hi, b2l, acc, 0,0,0);
                accRZ[nt] = acc;
            } else {
                f32x4 ax = accNX[nt-8], ah = accNH[nt-8];
                ax = __builtin_amdgcn_mfma_f32_16x16x32_bf16(a0hi, b0h, ax, 0,0,0);
                ax = __builtin_amdgcn_mfma_f32_16x16x32_bf16(a0lo, b0h, ax, 0,0,0);
                ax = __builtin_amdgcn_mfma_f32_16x16x32_bf16(a0hi, b0l, ax, 0,0,0);
                ah = __builtin_amdgcn_mfma_f32_16x16x32_bf16(a1hi, b1h, ah, 0,0,0);
                ah = __builtin_amdgcn_mfma_f32_16x16x32_bf16(a1lo, b1h, ah, 0,0,0);
                ah = __builtin_amdgcn_mfma_f32_16x16x32_bf16(a1hi, b1l, ah, 0,0,0);
                ah = __builtin_amdgcn_mfma_f32_16x16x32_bf16(a2hi, b2h, ah, 0,0,0);
                ah = __builtin_amdgcn_mfma_f32_16x16x32_bf16(a2lo, b2h, ah, 0,0,0);
                ah = __builtin_amdgcn_mfma_f32_16x16x32_bf16(a2hi, b2l, ah, 0,0,0);
                accNX[nt-8] = ax; accNH[nt-8] = ah;
            }
        }

        unsigned short* hbo = hbf + ((long)hop*NROWS + (long)n*64)*128;
        #pragma unroll
        for (int nt0=0; nt0<4; ++nt0){
            int hcol = nt0*16 + lr;
            float br  = bp[hcol];
            float bz  = bp[64 + hcol];
            float bxn = bp[128 + hcol];
            float bhn = bp[192 + hcol];
            #pragma unroll
            for (int i=0;i<4;i++){
                int orow = w*16 + lk*4 + i;        // C/D: row=(lane>>4)*4+reg, col=lane&15
                long off = (long)orow*128 + hcol;
                float hold = bf2f(hbo[off]) + bf2f(hbo[off+64]);
                float r  = sigm(accRZ[nt0][i] + br);
                float z  = sigm(accRZ[4+nt0][i] + bz);
                float nn2 = tanh_f(accNX[nt0][i] + bxn + r*(accNH[nt0][i] + bhn));
                float hv = (1.f - z)*nn2 + z*hold;
                unsigned short hvh = f2bf(hv);
                hbo[off] = hvh;
                hbo[off+64] = f2bf(hv - bf2f(hvh));
            }
        }
    }
}

// ---------------- fc + fused next-step feature build ----------------
__global__ void fc_k(const unsigned short* __restrict__ hbf, const float* __restrict__ fc_w,
                     const float* __restrict__ fc_b, const float* __restrict__ dec,
                     int p, float* __restrict__ xn_next, float* __restrict__ out)
{
    int idx = blockIdx.x*256+threadIdx.x;
    if (idx>=NROWS) return;
    float acc = fc_b[0];
    #pragma unroll
    for (int k=0;k<3;k++){
        const unsigned short* hb = hbf + ((size_t)k*NROWS + idx)*128;
        const float* wb = fc_w + k*HDIM;
        #pragma unroll
        for (int q=0;q<8;q++){
            short8 hi8 = *(const short8*)&hb[q*8];
            short8 lo8 = *(const short8*)&hb[64 + q*8];
            #pragma unroll
            for (int j=0;j<8;j++)
                acc += (bf2f((unsigned short)hi8[j]) + bf2f((unsigned short)lo8[j])) * wb[q*8+j];
        }
    }
    int b = idx & 63, n = idx >> 6;
    out[((long)b*PRED + p)*NNODE + n] = acc;
    if (xn_next){
        float* xp = xn_next + (long)n*FD*64 + b;
        xp[0] = acc;
        const float* fp = dec + (((long)b*PRED + (p+1))*NNODE + n)*FMD;
        #pragma unroll
        for (int i=0;i<FMD;i++) xp[(1+i)*64] = fp[i];
    }
}

extern "C" void kernel_launch(void* const* d_in, const int* in_sizes, int n_in,
                              void* d_out, int out_size, void* d_ws, size_t ws_size,
                              hipStream_t stream)
{
    const float* x_hist   = (const float*)d_in[0];
    const float* enc_misc = (const float*)d_in[1];
    const float* dec      = (const float*)d_in[2];
    const float* We       = (const float*)d_in[3];
    const float* be       = (const float*)d_in[4];
    const float* Wx       = (const float*)d_in[5];
    const float* Wh       = (const float*)d_in[6];
    const float* bx       = (const float*)d_in[7];
    const float* bh       = (const float*)d_in[8];
    const float* fc_w     = (const float*)d_in[9];
    const float* fc_b     = (const float*)d_in[10];
    const int*   src      = (const int*)d_in[11];
    const int*   dst      = (const int*)d_in[12];
    float* out = (float*)d_out;

    // ---- workspace carve (byte-based, 256-aligned) ----
    char* p = (char*)d_ws;
    auto alloc = [&](size_t bytes) -> char* {
        p = (char*)(((size_t)p + 255) & ~(size_t)255);
        char* r = p; p += bytes; return r;
    };
    unsigned short* hbf = (unsigned short*)alloc((size_t)3*NROWS*128*2);  // 53.3 MB
    unsigned short* Wt  = (unsigned short*)alloc((size_t)3*192*192*2);
    float* bpack = (float*)alloc(3*4*64*4);
    int* deg    = (int*)alloc(NNODE*4);
    int* offs   = (int*)alloc((NNODE+1)*4);
    int* curs   = (int*)alloc(NNODE*4);
    int* wpart  = (int*)alloc((WPAR+1)*4);
    int* esrc   = (int*)alloc(NE*4);

    const size_t perslice = (size_t)SZT*4*4;     // xn + 3 xg hops, f32
    size_t fixed_used = (size_t)(p - (char*)d_ws) + 8192;
    long T_CHUNK = 1;
    if (ws_size > fixed_used + perslice)
        T_CHUNK = (long)((ws_size - fixed_used) / perslice);
    if (T_CHUNK > HIST-1) T_CHUNK = HIST-1;
    if (T_CHUNK < 1) T_CHUNK = 1;

    float* xn_all = (float*)alloc((size_t)T_CHUNK*SZT*4);
    float* xg_all = (float*)alloc((size_t)3*T_CHUNK*SZT*4);
    const long K_STRIDE = T_CHUNK*SZT;

    hipMemsetAsync(hbf, 0, (size_t)3*NROWS*128*2, stream);
    hipMemsetAsync(deg, 0, NNODE*4, stream);

    const int gE = (NE+255)/256;
    csr_count_k<<<gE,256,0,stream>>>(dst, deg);
    csr_scan_k<<<1,1024,0,stream>>>(deg, offs, curs);
    csr_fill_k<<<gE,256,0,stream>>>(dst, src, curs, esrc);
    csr_part_k<<<(WPAR+256)/256,256,0,stream>>>(offs, wpart, WPAR);
    prep_k<<<(3*192*192+255)/256,256,0,stream>>>(Wx, Wh, bx, bh, Wt, bpack);

    const int gRow = (NROWS+255)/256;
    const int gGat = WPAR/4;               // 2048 blocks
    const dim3 gU((NNODE+3)/4, 3);         // 272 x 3

    // ---------------- history phase ----------------
    for (int t0 = 0; t0 < HIST-1; t0 += (int)T_CHUNK){
        int T = min((int)T_CHUNK, HIST-1-t0);
        build_hist_k<<<(int)(((long)T*NROWS+255)/256),256,0,stream>>>(x_hist, enc_misc, t0, T, xn_all);
        gnn_gather_k<<<gGat,256,0,stream>>>(xn_all,            We,be,esrc,offs,wpart, T, xg_all);
        gnn_gather_k<<<gGat,256,0,stream>>>(xg_all,            We,be,esrc,offs,wpart, T, xg_all+K_STRIDE);
        gnn_gather_k<<<gGat,256,0,stream>>>(xg_all+K_STRIDE,   We,be,esrc,offs,wpart, T, xg_all+2*K_STRIDE);
        for (int ti=0; ti<T; ti++)
            gru_mfma_k<<<gU,256,0,stream>>>(xg_all + ti*SZT, K_STRIDE,
                                            xn_all + ti*SZT, Wt, bpack, hbf);
    }

    // ---------------- prediction phase ----------------
    build_xn_k<<<gRow,256,0,stream>>>(x_hist, dec, xn_all);
    for (int pstep=0; pstep<PRED; pstep++){
        gnn_gather_k<<<gGat,256,0,stream>>>(xn_all,          We,be,esrc,offs,wpart, 1, xg_all);
        gnn_gather_k<<<gGat,256,0,stream>>>(xg_all,          We,be,esrc,offs,wpart, 1, xg_all+K_STRIDE);
        gnn_gather_k<<<gGat,256,0,stream>>>(xg_all+K_STRIDE, We,be,esrc,offs,wpart, 1, xg_all+2*K_STRIDE);
        gru_mfma_k<<<gU,256,0,stream>>>(xg_all, K_STRIDE, xn_all, Wt, bpack, hbf);
        fc_k<<<gRow,256,0,stream>>>(hbf, fc_w, fc_b, dec, pstep,
                                    (pstep < PRED-1) ? xn_all : nullptr, out);
    }
}

// Round 12
// 15132.692 us; speedup vs baseline: 3.3457x; 3.3457x over previous
//
#include <hip/hip_runtime.h>

#define NB 64
#define NNODE 1085
#define HIST 24
#define PRED 24
#define HDIM 64
#define FMD 11
#define FD 12
#define NE 17360
#define NROWS (NB*NNODE)     // 69440
#define SZT ((long)NROWS*FD) // f32 per t-slice, row-major (b,n,f): row = b*NNODE+n

// Layouts:
//  f32 node tensors [t][row][12], row = b*NNODE+n
//  bf16 hi/lo h: hbf[hop][row][128] (hi 0..63, lo 64..127)
//  bf16 hi/lo Wt: [hop][ncol=192][k=192] k:0..23 Wx^T hi, 24..31 0, 32..95 Wh^T hi; 96..191 lo
//  epack[e] = (dst<<12)|src, counting-sorted by dst

typedef float v4 __attribute__((ext_vector_type(4)));
typedef float f32x4 __attribute__((ext_vector_type(4)));
typedef short short8 __attribute__((ext_vector_type(8)));

__device__ __forceinline__ float sigm(float x){ return 1.0f/(1.0f + __expf(-x)); }
__device__ __forceinline__ float tanh_f(float x){ return 1.0f - 2.0f/(__expf(2.0f*x)+1.0f); }
__device__ __forceinline__ unsigned short f2bf(float f){
    union { float f; unsigned u; } v; v.f = f;
    unsigned r = v.u + 0x7FFF + ((v.u >> 16) & 1);
    return (unsigned short)(r >> 16);
}
__device__ __forceinline__ float bf2f(unsigned short u){
    union { unsigned u; float f; } v; v.u = ((unsigned)u)<<16; return v.f;
}

// ---------------- CSR build ----------------
__global__ void csr_count_k(const int* __restrict__ dst, int* __restrict__ deg)
{
    int e = blockIdx.x*256 + threadIdx.x;
    if (e < NE) atomicAdd(&deg[dst[e]], 1);
}

__global__ __launch_bounds__(1024) void csr_scan_k(const int* __restrict__ deg,
                                                   int* __restrict__ offs, int* __restrict__ curs)
{
    __shared__ int s[2][2048];
    int t = threadIdx.x;
    for (int i=t;i<2048;i+=1024) s[0][i] = (i<NNODE) ? deg[i] : 0;
    __syncthreads();
    int cur = 0;
    for (int d=1; d<2048; d<<=1){
        for (int i=t;i<2048;i+=1024){
            int v = s[cur][i];
            if (i>=d) v += s[cur][i-d];
            s[cur^1][i] = v;
        }
        __syncthreads();
        cur ^= 1;
    }
    for (int i=t;i<=NNODE;i+=1024){
        int v = (i==0) ? 0 : s[cur][i-1];
        offs[i] = v;
        if (i<NNODE) curs[i] = v;
    }
}

__global__ void csr_fill_k(const int* __restrict__ dst, const int* __restrict__ src,
                           int* __restrict__ curs, int* __restrict__ epack)
{
    int e = blockIdx.x*256 + threadIdx.x;
    if (e < NE){
        int d = dst[e];
        int p = atomicAdd(&curs[d], 1);
        epack[p] = (d<<12) | src[e];
    }
}

// ---------------- one-time prep: W -> transposed hi/lo bf16, bias pack ----------------
__global__ void prep_k(const float* __restrict__ Wx, const float* __restrict__ Wh,
                       const float* __restrict__ bx, const float* __restrict__ bh,
                       unsigned short* __restrict__ Wt, float* __restrict__ bpack)
{
    int id = blockIdx.x*256 + threadIdx.x;
    if (id < 3*192*192){
        int hop = id/(192*192); int rem = id - hop*192*192;
        int n = rem/192, kk = rem - n*192;
        int k2 = (kk < 96) ? kk : kk - 96;
        float v = 0.f;
        if (k2 < 24)       v = Wx[hop*24*192 + k2*192 + n];
        else if (k2 >= 32) v = Wh[hop*64*192 + (k2-32)*192 + n];
        unsigned short hi = f2bf(v);
        Wt[id] = (kk < 96) ? hi : f2bf(v - bf2f(hi));
    }
    if (id < 3*4*64){
        int hop = id/256; int rem = id - hop*256;
        int g = rem>>6, c = rem&63;
        const float* bxk = bx + hop*192; const float* bhk = bh + hop*192;
        float v;
        if (g==0)      v = bxk[c]     + bhk[c];
        else if (g==1) v = bxk[64+c]  + bhk[64+c];
        else if (g==2) v = bxk[128+c];
        else           v = bhk[128+c];
        bpack[id] = v;
    }
}

// ---------------- pred-0 feature build (row-major) ----------------
__global__ void build_xn_k(const float* __restrict__ x_hist,
                           const float* __restrict__ dec,
                           float* __restrict__ xn)
{
    int idx = blockIdx.x*256 + threadIdx.x;
    if (idx >= NROWS) return;
    int b = idx / NNODE, n = idx - b*NNODE;
    float* xp = xn + (long)idx*FD;
    xp[0] = x_hist[((long)b*HIST + (HIST-1))*NNODE + n];
    const float* fp = dec + ((long)b*PRED*NNODE + n)*FMD;
    #pragma unroll
    for (int i=0;i<FMD;i++) xp[1+i] = fp[i];
}

// ---------------- fused 3-hop GNN: one block = one (slice, batch), in-LDS ping-pong ----
// HISTM=1: builds xn in-kernel from x_hist/enc_misc (slice t0+ti) and writes it out.
// HISTM=0: stages prebuilt xn from global (T=1).
template<int HISTM>
__global__ __launch_bounds__(1024,1) void gather3_k(
    const float* __restrict__ x_hist, const float* __restrict__ enc_misc, int t0,
    const float* __restrict__ xn_g,
    const float* __restrict__ We, const float* __restrict__ be,
    const int* __restrict__ epack,
    float* __restrict__ xn_out,          // [ti][row][12] (HISTM only)
    float* __restrict__ xg_out,          // hop k at xg_out + k*hopstride + ti*SZT
    long hopstride)
{
    __shared__ __align__(16) float xa[NNODE*FD];   // 52080 B
    __shared__ __align__(16) float xb[NNODE*FD];   // 52080 B
    __shared__ float w_s[288];
    __shared__ float be_s[12];
    const int tid = threadIdx.x;
    const int b = blockIdx.x;
    const long ti = blockIdx.y;

    for (int i=tid;i<288;i+=1024) w_s[i]=We[i];
    if (tid<12) be_s[tid]=be[tid];

    if (HISTM){
        int t = t0 + (int)ti;
        for (int i=tid;i<NNODE;i+=1024) xa[i*12] = x_hist[((long)b*HIST + t)*NNODE + i];
        for (int i=tid;i<NNODE*FMD;i+=1024){
            int n = i/FMD, f = i - n*FMD;
            xa[n*12+1+f] = enc_misc[(((long)b*HIST + (t+1))*NNODE + n)*FMD + f];
        }
    } else {
        const v4* src = (const v4*)(xn_g + (long)b*NNODE*FD);
        for (int i=tid;i<NNODE*3;i+=1024) ((v4*)xa)[i] = src[i];
    }
    __syncthreads();
    if (HISTM){
        v4* dst = (v4*)(xn_out + ti*SZT + (long)b*NNODE*FD);
        for (int i=tid;i<NNODE*3;i+=1024) dst[i] = ((const v4*)xa)[i];
    }

    float* cur = xa;
    float* nxt = xb;
    const int L = (NE + 1023) >> 10;          // 17 edges/thread
    const int e0 = tid*L, e1 = min(e0+L, NE);

    #pragma unroll 1
    for (int hop=0; hop<3; ++hop){
        // nxt = cur (residual init)
        for (int i=tid;i<NNODE*3;i+=1024) ((v4*)nxt)[i] = ((const v4*)cur)[i];
        __syncthreads();

        float accr[12], part[12];
        int curd = -1;
        for (int e=e0; e<e1; ++e){
            int pk = epack[e];
            int dN = pk >> 12, sN = pk & 4095;
            if (dN != curd){
                if (curd >= 0){
                    float* ab = &nxt[curd*12];
                    #pragma unroll
                    for (int f=0;f<12;f++) atomicAdd(&ab[f], accr[f]);
                }
                curd = dN;
                #pragma unroll
                for (int f=0;f<12;f++){ accr[f]=0.f; part[f]=be_s[f]; }
                const float* xd = &cur[dN*12];
                #pragma unroll
                for (int f=0;f<12;f++){
                    float xv = xd[f];
                    const float* wrow = &w_s[(12+f)*12];
                    #pragma unroll
                    for (int j=0;j<12;j++) part[j] += xv*wrow[j];
                }
            }
            float m[12];
            #pragma unroll
            for (int f=0;f<12;f++) m[f]=part[f];
            const float* xs = &cur[sN*12];
            #pragma unroll
            for (int f=0;f<12;f++){
                float xv = xs[f];
                const float* wrow = &w_s[f*12];
                #pragma unroll
                for (int j=0;j<12;j++) m[j] += xv*wrow[j];
            }
            #pragma unroll
            for (int f=0;f<12;f++) accr[f] += fmaxf(m[f],0.f);
        }
        if (curd >= 0){
            float* ab = &nxt[curd*12];
            #pragma unroll
            for (int f=0;f<12;f++) atomicAdd(&ab[f], accr[f]);
        }
        __syncthreads();

        // write hop output to global (coalesced)
        v4* dst = (v4*)(xg_out + (long)hop*hopstride + ti*SZT + (long)b*NNODE*FD);
        for (int i=tid;i<NNODE*3;i+=1024) dst[i] = ((const v4*)nxt)[i];

        float* tmp = cur; cur = nxt; nxt = tmp;
        __syncthreads();
    }
}

// ---------------- split-precision MFMA GRU: 8 row-tiles/block, grid (136, 3) ----------------
__global__ __launch_bounds__(256,1) void gru_mfma_k(
    const float* __restrict__ xg_base, long hopstride,  // hop k xg = xg_base + k*hopstride
    const float* __restrict__ xn,
    const unsigned short* __restrict__ Wt,              // [hop][192][192]
    const float* __restrict__ bpack,                    // [hop][4][64]
    unsigned short* __restrict__ hbf)                   // [hop][NROWS][128] hi/lo
{
    __shared__ __align__(16) unsigned short Wt_s[192][200];
    const int tid = threadIdx.x;
    const int hop = blockIdx.y;

    const unsigned short* wtg = Wt + (size_t)hop*192*192;
    #pragma unroll
    for (int it=0; it<18; ++it){
        int i = tid + it*256;
        int r = i/24, o = i - r*24;
        *(short8*)&Wt_s[r][o*8] = *(const short8*)&wtg[r*192 + o*8];
    }
    __syncthreads();

    const int w = tid>>6, l = tid&63, lr = l&15, lk = l>>4;
    const float* bp = bpack + hop*256;
    const float* xg = xg_base + (long)hop*hopstride;

    const int tend = min(blockIdx.x*8 + 8, NROWS/64);
    for (int tile = blockIdx.x*8; tile < tend; ++tile){
        const long rowA = (long)tile*64 + w*16 + lr;

        // A k=0..23: [xg(12)|xn(12)] contiguous per row; k=24..31 pad
        short8 a0hi = short8(0), a0lo = short8(0);
        if (lk < 3){
            const float* xgr = xg + rowA*FD;
            const float* xnr = xn + rowA*FD;
            #pragma unroll
            for (int i=0;i<8;i++){
                int k = lk*8 + i;
                float v = (k<12) ? xgr[k] : xnr[k-12];
                unsigned short hi = f2bf(v);
                a0hi[i] = (short)hi;
                a0lo[i] = (short)f2bf(v - bf2f(hi));
            }
        }
        const unsigned short* hb = hbf + ((long)hop*NROWS + rowA)*128;
        short8 a1hi = *(const short8*)&hb[lk*8];
        short8 a2hi = *(const short8*)&hb[32 + lk*8];
        short8 a1lo = *(const short8*)&hb[64 + lk*8];
        short8 a2lo = *(const short8*)&hb[96 + lk*8];

        f32x4 accRZ[8], accNX[4], accNH[4];
        #pragma unroll
        for (int i=0;i<8;i++) accRZ[i] = f32x4(0.f);
        #pragma unroll
        for (int i=0;i<4;i++){ accNX[i] = f32x4(0.f); accNH[i] = f32x4(0.f); }

        #pragma unroll
        for (int nt=0; nt<12; ++nt){
            const unsigned short* wc = &Wt_s[nt*16 + lr][0];
            short8 b0h = *(const short8*)&wc[lk*8];
            short8 b1h = *(const short8*)&wc[32 + lk*8];
            short8 b2h = *(const short8*)&wc[64 + lk*8];
            short8 b0l = *(const short8*)&wc[96 + lk*8];
            short8 b1l = *(const short8*)&wc[128 + lk*8];
            short8 b2l = *(const short8*)&wc[160 + lk*8];
            if (nt < 8){
                f32x4 acc = accRZ[nt];
                acc = __builtin_amdgcn_mfma_f32_16x16x32_bf16(a0hi, b0h, acc, 0,0,0);
                acc = __builtin_amdgcn_mfma_f32_16x16x32_bf16(a0lo, b0h, acc, 0,0,0);
                acc = __builtin_amdgcn_mfma_f32_16x16x32_bf16(a0hi, b0l, acc, 0,0,0);
                acc = __builtin_amdgcn_mfma_f32_16x16x32_bf16(a1hi, b1h, acc, 0,0,0);
                acc = __builtin_amdgcn_mfma_f32_16x16x32_bf16(a1lo, b1h, acc, 0,0,0);
                acc = __builtin_amdgcn_mfma_f32_16x16x32_bf16(a1hi, b1l, acc, 0,0,0);
                acc = __builtin_amdgcn_mfma_f32_16x16x32_bf16(a2hi, b2h, acc, 0,0,0);
                acc = __builtin_amdgcn_mfma_f32_16x16x32_bf16(a2lo, b2h, acc, 0,0,0);
                acc = __builtin_amdgcn_mfma_f32_16x16x32_bf16(a2hi, b2l, acc, 0,0,0);
                accRZ[nt] = acc;
            } else {
                f32x4 ax = accNX[nt-8], ah = accNH[nt-8];
                ax = __builtin_amdgcn_mfma_f32_16x16x32_bf16(a0hi, b0h, ax, 0,0,0);
                ax = __builtin_amdgcn_mfma_f32_16x16x32_bf16(a0lo, b0h, ax, 0,0,0);
                ax = __builtin_amdgcn_mfma_f32_16x16x32_bf16(a0hi, b0l, ax, 0,0,0);
                ah = __builtin_amdgcn_mfma_f32_16x16x32_bf16(a1hi, b1h, ah, 0,0,0);
                ah = __builtin_amdgcn_mfma_f32_16x16x32_bf16(a1lo, b1h, ah, 0,0,0);
                ah = __builtin_amdgcn_mfma_f32_16x16x32_bf16(a1hi, b1l, ah, 0,0,0);
                ah = __builtin_amdgcn_mfma_f32_16x16x32_bf16(a2hi, b2h, ah, 0,0,0);
                ah = __builtin_amdgcn_mfma_f32_16x16x32_bf16(a2lo, b2h, ah, 0,0,0);
                ah = __builtin_amdgcn_mfma_f32_16x16x32_bf16(a2hi, b2l, ah, 0,0,0);
                accNX[nt-8] = ax; accNH[nt-8] = ah;
            }
        }

        unsigned short* hbo = hbf + ((long)hop*NROWS + (long)tile*64)*128;
        #pragma unroll
        for (int nt0=0; nt0<4; ++nt0){
            int hcol = nt0*16 + lr;
            float br  = bp[hcol];
            float bz  = bp[64 + hcol];
            float bxn = bp[128 + hcol];
            float bhn = bp[192 + hcol];
            #pragma unroll
            for (int i=0;i<4;i++){
                int orow = w*16 + lk*4 + i;        // C/D: row=(lane>>4)*4+reg, col=lane&15
                long off = (long)orow*128 + hcol;
                float hold = bf2f(hbo[off]) + bf2f(hbo[off+64]);
                float r  = sigm(accRZ[nt0][i] + br);
                float z  = sigm(accRZ[4+nt0][i] + bz);
                float nn2 = tanh_f(accNX[nt0][i] + bxn + r*(accNH[nt0][i] + bhn));
                float hv = (1.f - z)*nn2 + z*hold;
                unsigned short hvh = f2bf(hv);
                hbo[off] = hvh;
                hbo[off+64] = f2bf(hv - bf2f(hvh));
            }
        }
    }
}

// ---------------- fc + fused next-step feature build ----------------
__global__ void fc_k(const unsigned short* __restrict__ hbf, const float* __restrict__ fc_w,
                     const float* __restrict__ fc_b, const float* __restrict__ dec,
                     int p, float* __restrict__ xn_next, float* __restrict__ out)
{
    int idx = blockIdx.x*256+threadIdx.x;
    if (idx>=NROWS) return;
    float acc = fc_b[0];
    #pragma unroll
    for (int k=0;k<3;k++){
        const unsigned short* hb = hbf + ((size_t)k*NROWS + idx)*128;
        const float* wb = fc_w + k*HDIM;
        #pragma unroll
        for (int q=0;q<8;q++){
            short8 hi8 = *(const short8*)&hb[q*8];
            short8 lo8 = *(const short8*)&hb[64 + q*8];
            #pragma unroll
            for (int j=0;j<8;j++)
                acc += (bf2f((unsigned short)hi8[j]) + bf2f((unsigned short)lo8[j])) * wb[q*8+j];
        }
    }
    int b = idx / NNODE, n = idx - b*NNODE;
    out[((long)b*PRED + p)*NNODE + n] = acc;
    if (xn_next){
        float* xp = xn_next + (long)idx*FD;
        xp[0] = acc;
        const float* fp = dec + (((long)b*PRED + (p+1))*NNODE + n)*FMD;
        #pragma unroll
        for (int i=0;i<FMD;i++) xp[1+i] = fp[i];
    }
}

extern "C" void kernel_launch(void* const* d_in, const int* in_sizes, int n_in,
                              void* d_out, int out_size, void* d_ws, size_t ws_size,
                              hipStream_t stream)
{
    const float* x_hist   = (const float*)d_in[0];
    const float* enc_misc = (const float*)d_in[1];
    const float* dec      = (const float*)d_in[2];
    const float* We       = (const float*)d_in[3];
    const float* be       = (const float*)d_in[4];
    const float* Wx       = (const float*)d_in[5];
    const float* Wh       = (const float*)d_in[6];
    const float* bx       = (const float*)d_in[7];
    const float* bh       = (const float*)d_in[8];
    const float* fc_w     = (const float*)d_in[9];
    const float* fc_b     = (const float*)d_in[10];
    const int*   src      = (const int*)d_in[11];
    const int*   dst      = (const int*)d_in[12];
    float* out = (float*)d_out;

    // ---- workspace carve (byte-based, 256-aligned) ----
    char* p = (char*)d_ws;
    auto alloc = [&](size_t bytes) -> char* {
        p = (char*)(((size_t)p + 255) & ~(size_t)255);
        char* r = p; p += bytes; return r;
    };
    unsigned short* hbf = (unsigned short*)alloc((size_t)3*NROWS*128*2);  // 53.3 MB
    unsigned short* Wt  = (unsigned short*)alloc((size_t)3*192*192*2);
    float* bpack = (float*)alloc(3*4*64*4);
    int* deg    = (int*)alloc(NNODE*4);
    int* offs   = (int*)alloc((NNODE+1)*4);
    int* curs   = (int*)alloc(NNODE*4);
    int* epack  = (int*)alloc(NE*4);

    const size_t perslice = (size_t)SZT*4*4;     // xn + 3 xg hops, f32
    size_t fixed_used = (size_t)(p - (char*)d_ws) + 8192;
    long T_CHUNK = 1;
    if (ws_size > fixed_used + perslice)
        T_CHUNK = (long)((ws_size - fixed_used) / perslice);
    if (T_CHUNK > HIST-1) T_CHUNK = HIST-1;
    if (T_CHUNK < 1) T_CHUNK = 1;

    float* xn_all = (float*)alloc((size_t)T_CHUNK*SZT*4);
    float* xg_all = (float*)alloc((size_t)3*T_CHUNK*SZT*4);
    const long HOPSTR = T_CHUNK*SZT;

    hipMemsetAsync(hbf, 0, (size_t)3*NROWS*128*2, stream);
    hipMemsetAsync(deg, 0, NNODE*4, stream);

    const int gE = (NE+255)/256;
    csr_count_k<<<gE,256,0,stream>>>(dst, deg);
    csr_scan_k<<<1,1024,0,stream>>>(deg, offs, curs);
    csr_fill_k<<<gE,256,0,stream>>>(dst, src, curs, epack);
    prep_k<<<(3*192*192+255)/256,256,0,stream>>>(Wx, Wh, bx, bh, Wt, bpack);

    const int gRow = (NROWS+255)/256;
    const dim3 gU((NROWS/64 + 7)/8, 3);          // 136 x 3

    // ---------------- history phase ----------------
    for (int t0 = 0; t0 < HIST-1; t0 += (int)T_CHUNK){
        int T = min((int)T_CHUNK, HIST-1-t0);
        dim3 gG(NB, T);
        gather3_k<1><<<gG,1024,0,stream>>>(x_hist, enc_misc, t0, nullptr,
                                           We, be, epack, xn_all, xg_all, HOPSTR);
        for (int ti=0; ti<T; ti++)
            gru_mfma_k<<<gU,256,0,stream>>>(xg_all + ti*SZT, HOPSTR,
                                            xn_all + ti*SZT, Wt, bpack, hbf);
    }

    // ---------------- prediction phase ----------------
    build_xn_k<<<gRow,256,0,stream>>>(x_hist, dec, xn_all);
    for (int pstep=0; pstep<PRED; pstep++){
        dim3 gG(NB, 1);
        gather3_k<0><<<gG,1024,0,stream>>>(nullptr, nullptr, 0, xn_all,
                                           We, be, epack, nullptr, xg_all, HOPSTR);
        gru_mfma_k<<<gU,256,0,stream>>>(xg_all, HOPSTR, xn_all, Wt, bpack, hbf);
        fc_k<<<gRow,256,0,stream>>>(hbf, fc_w, fc_b, dec, pstep,
                                    (pstep < PRED-1) ? xn_all : nullptr, out);
    }
}